// Round 6
// baseline (64.708 us; speedup 1.0000x reference)
//
#include <hip/hip_runtime.h>
#include <hip/hip_bf16.h>
#include <stdint.h>

#define N 4096
#define K 2048            // elements per row; i8 row = 2048 bytes
#define BT 256            // block tile (256x256)
#define KTB 128           // K-elems (=bytes) staged per K-tile
#define NKT (K / KTB)     // 16
#define NB (N / BT)       // 16
#define QS 25.4f          // 127/5: quantization scale (clip at 5 sigma)
#define SCL2 (1.0f / (QS * QS))
#define SHIFT 64.0f       // fixed softmax shift; d in [0,~71] -> e^{+-(d-64)} safe in fp32

typedef int i32x4 __attribute__((ext_vector_type(4)));
typedef unsigned int u32;

// async 16B global -> LDS (DMA; LDS dest = wave-uniform base + lane*16)
__device__ __forceinline__ void gload16(const void* g, void* l) {
    __builtin_amdgcn_global_load_lds((const __attribute__((address_space(1))) u32*)g,
                                     (__attribute__((address_space(3))) u32*)l, 16, 0, 0);
}

__device__ __forceinline__ int q8(float x) {
    return __float2int_rn(fminf(fmaxf(x * QS, -127.f), 127.f));
}

// --- kernel 1: row squared-norms (exact fp32) + fp32 -> i8 quantize ---------
__global__ __launch_bounds__(256) void k_prep(const float* __restrict__ X,
                                              char* __restrict__ Xq,
                                              float* __restrict__ sq) {
    const int row  = blockIdx.x * 4 + (threadIdx.x >> 6);
    const int lane = threadIdx.x & 63;
    const float4* xr = (const float4*)(X + (size_t)row * K);
    int* qr = (int*)(Xq + (size_t)row * K);  // 4 x i8 per int
    float s = 0.f;
#pragma unroll
    for (int i = 0; i < 8; ++i) {
        int idx = lane + i * 64;
        float4 v = xr[idx];
        int q0 = q8(v.x), q1 = q8(v.y), q2 = q8(v.z), q3 = q8(v.w);
        s += v.x * v.x + v.y * v.y + v.z * v.z + v.w * v.w;
        qr[idx] = (q0 & 255) | ((q1 & 255) << 8) | ((q2 & 255) << 16) | ((q3 & 255) << 24);
    }
#pragma unroll
    for (int off = 32; off > 0; off >>= 1) s += __shfl_xor(s, off);
    if (lane == 0) sq[row] = s;
}

// --- kernel 2: 256x256 i8 Gram tile, 8-phase schedule + shifted-exp sums ----
// 8 waves (512 thr), wave grid 2M x 4N, per-wave output 128x64.
// LDS: 2 buffers x 64KB (A 256x128B | B 256x128B). XOR swizzle (slot^(row&7))
// applied on the GLOBAL source column (LDS written linearly by gload_lds);
// read side applies the same involution.
__global__ __launch_bounds__(512, 2) void k_tile(const char* __restrict__ Xq,
                                                 const int* __restrict__ tg,
                                                 const float* __restrict__ sq,
                                                 float* __restrict__ part) {
    __shared__ __align__(1024) char lds[131072];
    const int tid = threadIdx.x;
    const int cb = blockIdx.x, rb = blockIdx.y;
    const int lane = tid & 63;
    const int wid = tid >> 6;
    const int wm = wid >> 2, wn = wid & 3;   // wave tile: rows wm*128, cols wn*64
    const int l15 = lane & 15, l4 = lane >> 4;

    // staging geometry: issue j (0..7): j<4 -> A rows [(j&3)*64,+64), j>=4 -> B.
    // thread t covers row t>>3, slot t&7 of that 64-row group.
    const int rsel = lane >> 3;            // 0..7
    const int csel = (lane & 7) ^ rsel;    // pre-swizzled 16B source slot
    const char* gA0 = Xq + (size_t)(rb * BT + wid * 8 + rsel) * K + csel * 16;
    const char* gB0 = Xq + (size_t)(cb * BT + wid * 8 + rsel) * K + csel * 16;

#define GLOAD(j, tile, buf) \
    gload16(((j) < 4 ? gA0 : gB0) + ((j) & 3) * (64 * K) + (size_t)(tile) * KTB, \
            (buf) + ((j) < 4 ? 0 : 32768) + ((j) & 3) * 8192 + wid * 1024)

#define RD_A(mh, ks) do { \
    _Pragma("unroll") for (int i = 0; i < 4; ++i) { \
        int row = wm * 128 + (mh) * 64 + i * 16 + l15; \
        a[i] = *(const i32x4*)(bufc + row * 128 + ((((ks) * 4 + l4) ^ (row & 7)) << 4)); } \
} while (0)

#define RD_B(ks, bb) do { \
    _Pragma("unroll") for (int i = 0; i < 4; ++i) { \
        int row = wn * 64 + i * 16 + l15; \
        bb[i] = *(const i32x4*)(bufc + 32768 + row * 128 + ((((ks) * 4 + l4) ^ (row & 7)) << 4)); } \
} while (0)

// swapped operands (T12 trick): acc = C^T -> output row is lane-fixed (l15)
#define MMA(mtb, bb) do { \
    __builtin_amdgcn_s_setprio(1); \
    _Pragma("unroll") for (int i = 0; i < 4; ++i) \
    _Pragma("unroll") for (int nt = 0; nt < 4; ++nt) \
        acc[(mtb) + i][nt] = __builtin_amdgcn_mfma_i32_16x16x64_i8(bb[nt], a[i], acc[(mtb) + i][nt], 0, 0, 0); \
    __builtin_amdgcn_s_setprio(0); \
} while (0)

#define BAR()   __builtin_amdgcn_s_barrier()
#define LGKM0() do { asm volatile("s_waitcnt lgkmcnt(0)" ::: "memory"); \
                     __builtin_amdgcn_sched_barrier(0); } while (0)
#define VM0()   do { asm volatile("s_waitcnt vmcnt(0)" ::: "memory"); \
                     __builtin_amdgcn_sched_barrier(0); } while (0)

    i32x4 acc[8][4] = {};

    // prologue: stage K-tile 0 into buf0
    GLOAD(0, 0, lds); GLOAD(1, 0, lds); GLOAD(2, 0, lds); GLOAD(3, 0, lds);
    GLOAD(4, 0, lds); GLOAD(5, 0, lds); GLOAD(6, 0, lds); GLOAD(7, 0, lds);
    VM0();
    BAR();

    for (int kt = 0; kt < NKT; ++kt) {
        const char* bufc = lds + (kt & 1) * 65536;
        char* bufn = lds + ((kt + 1) & 1) * 65536;
        const bool st = (kt + 1 < NKT);
        i32x4 a[4], b0[4], b1[4];
        // phase 0: ks=0, M-half 0 (+ B frags ks0)
        RD_B(0, b0); RD_A(0, 0);
        if (st) { GLOAD(0, kt + 1, bufn); GLOAD(1, kt + 1, bufn); }
        BAR(); LGKM0(); MMA(0, b0); BAR();
        // phase 1: ks=0, M-half 1 (reuse b0)
        RD_A(1, 0);
        if (st) { GLOAD(2, kt + 1, bufn); GLOAD(3, kt + 1, bufn); }
        BAR(); LGKM0(); MMA(4, b0); BAR();
        // phase 2: ks=1, M-half 0 (+ B frags ks1)
        RD_B(1, b1); RD_A(0, 1);
        if (st) { GLOAD(4, kt + 1, bufn); GLOAD(5, kt + 1, bufn); }
        BAR(); LGKM0(); MMA(0, b1); BAR();
        // phase 3: ks=1, M-half 1; buffer-ready check AFTER the MFMA cluster
        RD_A(1, 1);
        if (st) { GLOAD(6, kt + 1, bufn); GLOAD(7, kt + 1, bufn); }
        BAR(); LGKM0(); MMA(4, b1);
        VM0();   // next tile resident (loads aged >= 1 phase + MFMA cluster)
        BAR();
    }

    // ---- epilogue: shifted-exp partial sums; reduction axis lane-local -----
    // output row r = rb*256 + wm*128 + mt*16 + l15 (lane-fixed)
    // output col c = cb*256 + wn*64 + nt*16 + l4*4 + rg (in registers)
    float sqc[16]; int tgc[16];
#pragma unroll
    for (int nt = 0; nt < 4; ++nt)
#pragma unroll
        for (int rg = 0; rg < 4; ++rg) {
            int c = cb * BT + wn * 64 + nt * 16 + l4 * 4 + rg;
            sqc[nt * 4 + rg] = sq[c];
            tgc[nt * 4 + rg] = tg[c];
        }
#pragma unroll
    for (int mt = 0; mt < 8; ++mt) {
        int r = rb * BT + wm * 128 + mt * 16 + l15;
        float sqr = sq[r];
        int tgr = tg[r];
        float sp = 0.f, tp = 0.f, sn = 0.f, tn = 0.f;
#pragma unroll
        for (int nt = 0; nt < 4; ++nt)
#pragma unroll
            for (int rg = 0; rg < 4; ++rg) {
                float g = SCL2 * (float)acc[mt][nt][rg];
                float dd = sqrtf(fmaxf(sqr + sqc[nt * 4 + rg] - 2.0f * g, 1e-12f));
                bool pos = (tgr == tgc[nt * 4 + rg]);
                float e = __expf(pos ? (dd - SHIFT) : (SHIFT - dd));
                float ed = e * dd;
                if (pos) { sp += e; tp += ed; }
                else     { sn += e; tn += ed; }
            }
        // combine the 4 lanes (l4 = 0..3) sharing this row
#pragma unroll
        for (int off = 16; off < 64; off <<= 1) {
            sp += __shfl_xor(sp, off);
            tp += __shfl_xor(tp, off);
            sn += __shfl_xor(sn, off);
            tn += __shfl_xor(tn, off);
        }
        if (l4 == 0) {
            float4 v = {sp, tp, sn, tn};
            *(float4*)(part + (((size_t)(cb * 4 + wn) * N) + r) * 4) = v;
        }
    }
}

// --- kernel 3: sum 64 slot partials per row -> hinge -> mean (atomic) -------
__global__ __launch_bounds__(256) void k_final(const float* __restrict__ part,
                                               float* __restrict__ out) {
    int r = blockIdx.x * 256 + threadIdx.x;
    float sp = 0.f, tp = 0.f, sn = 0.f, tn = 0.f;
    for (int s = 0; s < 64; ++s) {
        float4 v = *(const float4*)(part + (((size_t)s * N) + r) * 4);
        sp += v.x; tp += v.y; sn += v.z; tn += v.w;
    }
    float h = fmaxf(tp / sp - tn / sn + 0.3f, 0.f);
    __shared__ float red[256];
    red[threadIdx.x] = h;
    __syncthreads();
    for (int k2 = 128; k2 > 0; k2 >>= 1) {
        if (threadIdx.x < k2) red[threadIdx.x] += red[threadIdx.x + k2];
        __syncthreads();
    }
    if (threadIdx.x == 0) atomicAdd(out, red[0] * (1.0f / N));
}

extern "C" void kernel_launch(void* const* d_in, const int* in_sizes, int n_in,
                              void* d_out, int out_size, void* d_ws, size_t ws_size,
                              hipStream_t stream) {
    (void)in_sizes; (void)n_in; (void)out_size; (void)ws_size;
    const float* X  = (const float*)d_in[0];
    const int*   tg = (const int*)d_in[1];

    char* ws = (char*)d_ws;
    float* sq   = (float*)ws;                  // 16 KB
    float* part = (float*)(ws + 32768);        // 64*4096*4 floats = 4 MB
    char*  Xq   = ws + 4227072;                // 8 MB i8

    hipMemsetAsync(d_out, 0, sizeof(float), stream);
    k_prep<<<N / 4, 256, 0, stream>>>(X, Xq, sq);
    k_tile<<<dim3(NB, NB), 512, 0, stream>>>(Xq, tg, sq, part);
    k_final<<<N / 256, 256, 0, stream>>>(part, (float*)d_out);
}